// Round 1
// baseline (236.738 us; speedup 1.0000x reference)
//
#include <hip/hip_runtime.h>

#define N_NODES 50000
#define N_EDGES 1600000
#define DIM 64
#define NBK 196          // buckets of 256 dst-nodes
#define BIN_BLOCKS 391   // ceil(1.6M / 4096)
#define CSR_CAP 12288    // per-bucket slots
#define QCAP 3072        // per-quarter slots (mult-16-padded mean ~2560, ~8-sigma margin)
#define GEMM_BLOCKS 197  // covers 50000 rows + dummy zero row
#define NB_AGG 12500     // aggregate blocks (4 nodes/block; 12500*4 == 50000 exactly)

// f32 -> bf16 round-to-nearest-even
__device__ __forceinline__ unsigned short f2bf(float f) {
    union { float f; unsigned u; } v; v.f = f;
    unsigned r = v.u + 0x7FFF + ((v.u >> 16) & 1);
    return (unsigned short)(r >> 16);
}
__device__ __forceinline__ float bf2f(unsigned short h) {
    union { unsigned u; float f; } v; v.u = ((unsigned)h) << 16;  return v.f;
}
// packed-bf16 halves of a uint -> f32 (low ushort, high ushort)
__device__ __forceinline__ float blo(unsigned u) {
    union { unsigned u; float f; } v; v.u = u << 16; return v.f;
}
__device__ __forceinline__ float bhi(unsigned u) {
    union { unsigned u; float f; } v; v.u = u & 0xFFFF0000u; return v.f;
}

// R11-verbatim fused kernel: blocks [0, BIN_BLOCKS) bin edges into per-bucket
// regions (bcur zero-based, memset first); blocks [BIN_BLOCKS, ..) T=feat@W1^T.
// NO ncnt histogram (R14: 1.6M global atomics cost ~50us). NO min-waves clause
// (R13: forcing 64 VGPR spilled the binning arrays -> 358us).
__global__ __launch_bounds__(256) void bin_and_gemm1(const int* __restrict__ src,
                                                     const int* __restrict__ dst,
                                                     int* __restrict__ bcur,
                                                     int* __restrict__ binned,
                                                     const float* __restrict__ X,
                                                     const float* __restrict__ W,
                                                     unsigned short* __restrict__ T) {
    __shared__ int cnt[NBK];
    __shared__ int lofs[NBK];
    __shared__ int shiftv[NBK];
    __shared__ int sb[256];
    __shared__ int stag[4096];
    __shared__ unsigned char stb[4096];
    __shared__ float Ws[64 * 64];
    int tid = threadIdx.x;

    if (blockIdx.x >= BIN_BLOCKS) {
        // ---------------- GEMM path (feat f32 -> T bf16) ----------------
#pragma unroll
        for (int j = 0; j < 16; ++j) Ws[j * 256 + tid] = W[j * 256 + tid];
        __syncthreads();

        int n = (blockIdx.x - BIN_BLOCKS) * 256 + tid;
        if (n > N_NODES) return;
        ushort4* tp = (ushort4*)(T + (size_t)n * 64);
        if (n == N_NODES) {  // dummy zero row (pad target for agg1)
            ushort4 z = {0, 0, 0, 0};
#pragma unroll
            for (int k = 0; k < 16; ++k) tp[k] = z;
            return;
        }

        float4 x[16];
        const float4* xp = (const float4*)(X + (size_t)n * 64);
#pragma unroll
        for (int k = 0; k < 16; ++k) x[k] = xp[k];

        for (int fg = 0; fg < 16; ++fg) {
            float r[4];
#pragma unroll
            for (int fi = 0; fi < 4; ++fi) {
                int f = fg * 4 + fi;
                float acc = 0.f;
#pragma unroll
                for (int k4 = 0; k4 < 16; ++k4) {
                    float4 w = *(const float4*)&Ws[f * 64 + k4 * 4];
                    float4 xv = x[k4];
                    acc += xv.x * w.x + xv.y * w.y + xv.z * w.z + xv.w * w.w;
                }
                r[fi] = acc;
            }
            ushort4 o;
            o.x = f2bf(r[0]); o.y = f2bf(r[1]); o.z = f2bf(r[2]); o.w = f2bf(r[3]);
            tp[fg] = o;
        }
        return;
    }

    // ---------------- Binning path (R6-proven) ----------------
    if (tid < NBK) cnt[tid] = 0;
    __syncthreads();

    int base = blockIdx.x * 4096;
    int nedge = N_EDGES - base;
    if (nedge > 4096) nedge = 4096;

    int myb[16], myr[16], myp[16];
#pragma unroll
    for (int i = 0; i < 16; ++i) {
        int e = base + i * 256 + tid;
        myb[i] = -1;
        if (e < N_EDGES) {
            int s = src[e], d = dst[e];
            int b = d >> 8;
            myb[i] = b;
            myp[i] = ((d & 255) << 16) | s;
            myr[i] = atomicAdd(&cnt[b], 1);
        }
    }
    __syncthreads();

    int c = (tid < NBK) ? cnt[tid] : 0;
    sb[tid] = c;
    __syncthreads();
    for (int off = 1; off < 256; off <<= 1) {
        int u = (tid >= off) ? sb[tid - off] : 0;
        __syncthreads();
        sb[tid] += u;
        __syncthreads();
    }
    if (tid < NBK) {
        lofs[tid] = sb[tid] - c;
        if (c) shiftv[tid] = tid * CSR_CAP + atomicAdd(&bcur[tid * 16], c) - lofs[tid];
    }
    __syncthreads();

#pragma unroll
    for (int i = 0; i < 16; ++i) {
        if (myb[i] >= 0) {
            int idx = lofs[myb[i]] + myr[i];
            stag[idx] = myp[i];
            stb[idx] = (unsigned char)myb[i];
        }
    }
    __syncthreads();

    for (int i = tid; i < nedge; i += 256)
        binned[i + shiftv[stb[i]]] = stag[i];
}

// R11-verbatim: one workgroup per (bucket, dst-quarter). Counts padded to
// mult-16 with dummy src = N_NODES (zero row). nodeinfo=(pcnt<<23)|pos, pos%16==0.
__global__ __launch_bounds__(256) void build_csr(const int* __restrict__ binned,
                                                 const int* __restrict__ bcur,
                                                 unsigned* __restrict__ nodeinfo,
                                                 unsigned short* __restrict__ csr16) {
    __shared__ int cnt[64], cnt2[64], ofs[64], sb[64];
    __shared__ int qtot;
    int tid = threadIdx.x;
    int b = blockIdx.x >> 2;
    int q = blockIdx.x & 3;
    int ibase = b * CSR_CAP;
    int qbase = (b * 4 + q) * QCAP;
    int m = bcur[b * 16];          // zero-based bucket edge count
    if (m > CSR_CAP) m = CSR_CAP;
    if (tid < 64) { cnt[tid] = 0; cnt2[tid] = 0; }
    __syncthreads();

    for (int i = tid; i < m; i += 256) {
        int dl = (binned[ibase + i] >> 16) & 255;
        if ((dl >> 6) == q) atomicAdd(&cnt[dl & 63], 1);
    }
    __syncthreads();

    int v = 0;
    if (tid < 64) { v = (cnt[tid] + 15) & ~15; sb[tid] = v; }  // mult-16 pad
    __syncthreads();
    for (int off = 1; off < 64; off <<= 1) {
        int u = (tid >= off && tid < 64) ? sb[tid - off] : 0;
        __syncthreads();
        if (tid < 64) sb[tid] += u;
        __syncthreads();
    }
    if (tid < 64) {
        ofs[tid] = sb[tid] - v;
        int node = (b << 8) + (q << 6) + tid;
        if (node < N_NODES)
            nodeinfo[node] = ((unsigned)v << 23) | (unsigned)(qbase + ofs[tid]);
    }
    if (tid == 63) qtot = sb[63];
    __syncthreads();

    int qt = qtot;
    for (int i = tid; i < qt; i += 256) csr16[qbase + i] = (unsigned short)N_NODES;
    __syncthreads();

    for (int i = tid; i < m; i += 256) {
        int p = binned[ibase + i];
        int dl = (p >> 16) & 255;
        if ((dl >> 6) == q) {
            int r = atomicAdd(&cnt2[dl & 63], 1);
            csr16[qbase + ofs[dl & 63] + r] = (unsigned short)(p & 0xFFFF);
        }
    }
}

// Layer-1 aggregate FUSED with the layer-2 transform.
// R16 restructure: 8-lanes-per-row gather. A T row is 128B = 8 lanes x uint4,
// so one global_load_dwordx4 fetches EIGHT src rows per wave (1KB/inst) vs the
// old one-row-per-inst ushort gather. Per 8 edges: 1 idx load + 1 data load +
// ~20 VALU (was 8 loads + ~45 VALU). Lane (g8=lane>>3, fs=lane&7) accumulates
// features fs*8..fs*8+7 for edge subset g8 mod 8; an in-wave 8x8 LDS transpose
// (part[]) reduces groups and lands h in lane=feature layout for the fused
// W2 epilogue. Grid exactly covers 50000 nodes (barrier-uniform).
__global__ __launch_bounds__(256) void agg_fuse1(const unsigned short* __restrict__ T,
                                                 const unsigned short* __restrict__ csr,
                                                 const unsigned* __restrict__ nodeinfo,
                                                 const float* __restrict__ b1,
                                                 const float* __restrict__ W2,
                                                 unsigned short* __restrict__ T2) {
    __shared__ float4 W2t4[1024];     // 16 KB  (W2 transposed, lane-striped)
    __shared__ float part[4][8][64];  // 8 KB   (per-wave 8-group partials)
    __shared__ float hsf[4 * 64];     // 1 KB   (one h-row per wave)
    int tid = threadIdx.x;
    int w = tid >> 6;
    int lane = tid & 63;
    int g8 = lane >> 3;
    int fs = lane & 7;
    int node = blockIdx.x * 4 + w;

    // stage W2 transposed (read after the first barrier below)
    for (int L4 = tid; L4 < 1024; L4 += 256) {
        int k4 = L4 >> 6, f = L4 & 63;
        W2t4[L4] = *(const float4*)(W2 + f * 64 + k4 * 4);
    }

    // ---- gather-accumulate: 8 rows per load instruction ----
    unsigned info = nodeinfo[node];
    int pos = (int)(info & 0x7FFFFFu);
    int nch = (int)(info >> 23) >> 3;   // 8-edge chunks, always even (pcnt mult 16)
    const unsigned short* ip = csr + pos + g8;
    const uint4* Tp = (const uint4*)T;
    float a0 = 0.f, a1 = 0.f, a2 = 0.f, a3 = 0.f, a4 = 0.f, a5 = 0.f, a6 = 0.f, a7 = 0.f;
    float c0 = 0.f, c1 = 0.f, c2 = 0.f, c3 = 0.f, c4 = 0.f, c5 = 0.f, c6 = 0.f, c7 = 0.f;
    for (int c = 0; c < nch; c += 2) {
        int i0 = ip[c * 8];
        int i1 = ip[c * 8 + 8];
        uint4 da = Tp[(size_t)i0 * 8 + fs];
        uint4 db = Tp[(size_t)i1 * 8 + fs];
        a0 += blo(da.x); a1 += bhi(da.x);
        a2 += blo(da.y); a3 += bhi(da.y);
        a4 += blo(da.z); a5 += bhi(da.z);
        a6 += blo(da.w); a7 += bhi(da.w);
        c0 += blo(db.x); c1 += bhi(db.x);
        c2 += blo(db.y); c3 += bhi(db.y);
        c4 += blo(db.z); c5 += bhi(db.z);
        c6 += blo(db.w); c7 += bhi(db.w);
    }
    float4 pa = {a0 + c0, a1 + c1, a2 + c2, a3 + c3};
    float4 pb = {a4 + c4, a5 + c5, a6 + c6, a7 + c7};
    *(float4*)&part[w][g8][fs * 8] = pa;
    *(float4*)&part[w][g8][fs * 8 + 4] = pb;
    __syncthreads();   // covers W2t4 staging + part writes

    // reduce 8 groups: lane = feature
    float acc = b1[lane];
#pragma unroll
    for (int g = 0; g < 8; ++g) acc += part[w][g][lane];

    // ---- tanh + in-block 64x64 GEMM epilogue ----
    float e = __expf(2.f * acc);
    hsf[w * 64 + lane] = 1.f - 2.f / (e + 1.f);
    __syncthreads();   // hsf visibility

    const float4* hv4 = (const float4*)&hsf[w * 64];
    float tf = 0.f;
#pragma unroll
    for (int k4 = 0; k4 < 16; ++k4) {
        float4 hv = hv4[k4];             // broadcast
        float4 wv = W2t4[k4 * 64 + lane];
        tf += hv.x * wv.x + hv.y * wv.y + hv.z * wv.z + hv.w * wv.w;
    }
    T2[(size_t)node * DIM + lane] = f2bf(tf);

    // zero T2's dummy pad row (block 0 only; agg2 gathers it for padding)
    if (blockIdx.x == 0 && tid < 64)
        T2[(size_t)N_NODES * DIM + tid] = 0;
}

// Layer-2 aggregate: out = gather-sum(T2) + b2, f32. Same 8-lanes-per-row
// gather + in-wave LDS transpose reduce as agg_fuse1.
__global__ __launch_bounds__(256) void agg_out(const unsigned short* __restrict__ T,
                                               const unsigned short* __restrict__ csr,
                                               const unsigned* __restrict__ nodeinfo,
                                               const float* __restrict__ bias,
                                               float* __restrict__ outp) {
    __shared__ float part[4][8][64];  // 8 KB
    int tid = threadIdx.x;
    int w = tid >> 6;
    int lane = tid & 63;
    int g8 = lane >> 3;
    int fs = lane & 7;
    int node = blockIdx.x * 4 + w;    // grid*4 == 50000 exactly, no guard needed

    unsigned info = nodeinfo[node];
    int pos = (int)(info & 0x7FFFFFu);
    int nch = (int)(info >> 23) >> 3;
    const unsigned short* ip = csr + pos + g8;
    const uint4* Tp = (const uint4*)T;
    float a0 = 0.f, a1 = 0.f, a2 = 0.f, a3 = 0.f, a4 = 0.f, a5 = 0.f, a6 = 0.f, a7 = 0.f;
    float c0 = 0.f, c1 = 0.f, c2 = 0.f, c3 = 0.f, c4 = 0.f, c5 = 0.f, c6 = 0.f, c7 = 0.f;
    for (int c = 0; c < nch; c += 2) {
        int i0 = ip[c * 8];
        int i1 = ip[c * 8 + 8];
        uint4 da = Tp[(size_t)i0 * 8 + fs];
        uint4 db = Tp[(size_t)i1 * 8 + fs];
        a0 += blo(da.x); a1 += bhi(da.x);
        a2 += blo(da.y); a3 += bhi(da.y);
        a4 += blo(da.z); a5 += bhi(da.z);
        a6 += blo(da.w); a7 += bhi(da.w);
        c0 += blo(db.x); c1 += bhi(db.x);
        c2 += blo(db.y); c3 += bhi(db.y);
        c4 += blo(db.z); c5 += bhi(db.z);
        c6 += blo(db.w); c7 += bhi(db.w);
    }
    float4 pa = {a0 + c0, a1 + c1, a2 + c2, a3 + c3};
    float4 pb = {a4 + c4, a5 + c5, a6 + c6, a7 + c7};
    *(float4*)&part[w][g8][fs * 8] = pa;
    *(float4*)&part[w][g8][fs * 8 + 4] = pb;
    __syncthreads();

    float acc = bias[lane];
#pragma unroll
    for (int g = 0; g < 8; ++g) acc += part[w][g][lane];
    outp[(size_t)node * DIM + lane] = acc;
}

extern "C" void kernel_launch(void* const* d_in, const int* in_sizes, int n_in,
                              void* d_out, int out_size, void* d_ws, size_t ws_size,
                              hipStream_t stream) {
    const float* feat = (const float*)d_in[0];
    const int*   src  = (const int*)d_in[1];
    const int*   dst  = (const int*)d_in[2];
    const float* W1   = (const float*)d_in[3];
    const float* b1   = (const float*)d_in[4];
    const float* W2   = (const float*)d_in[5];
    const float* b2   = (const float*)d_in[6];
    float* out = (float*)d_out;

    // ws layout (~27.9 MB; harness poisons 256 MB of ws -> plenty)
    int*            binned   = (int*)d_ws;                                // 196*12288 ints
    unsigned short* csr16    = (unsigned short*)(binned + NBK * CSR_CAP); // 784*3072 ushort
    unsigned*       nodeinfo = (unsigned*)(csr16 + NBK * 4 * QCAP);       // 50000
    int*            bcur     = (int*)(nodeinfo + N_NODES);                // 196*16
    unsigned short* t        = (unsigned short*)(bcur + NBK * 16 + 8);    // 50001*64 bf16
    unsigned short* t2       = t + (size_t)(N_NODES + 1) * 64;            // 50001*64 bf16

    // ---- CSR build + layer-1 transform (overlapped) ----
    hipMemsetAsync(bcur, 0, NBK * 16 * sizeof(int), stream);
    bin_and_gemm1<<<BIN_BLOCKS + GEMM_BLOCKS, 256, 0, stream>>>(
        src, dst, bcur, binned, feat, W1, t);
    build_csr<<<NBK * 4, 256, 0, stream>>>(binned, bcur, nodeinfo, csr16);

    // ---- Layer 1 aggregate + fused layer-2 transform: t2 = tanh(agg+b1)@W2^T ----
    agg_fuse1<<<NB_AGG, 256, 0, stream>>>(t, csr16, nodeinfo, b1, W2, t2);

    // ---- Layer 2 aggregate: out = agg(t2) + b2, f32 ----
    agg_out<<<NB_AGG, 256, 0, stream>>>(t2, csr16, nodeinfo, b2, out);
}

// Round 2
// 224.646 us; speedup vs baseline: 1.0538x; 1.0538x over previous
//
#include <hip/hip_runtime.h>

#define N_NODES 50000
#define N_EDGES 1600000
#define DIM 64
#define NBK 196          // buckets of 256 dst-nodes
#define BIN_BLOCKS 391   // ceil(1.6M / 4096)
#define CSR_CAP 12288    // per-bucket slots
#define QCAP 3072        // per-quarter slots (mult-16-padded mean ~2560, ~8-sigma margin)
#define GEMM_BLOCKS 197  // covers 50000 rows + dummy zero row
#define NB_AGG8 6250     // aggregate blocks (8 nodes/block; 6250*8 == 50000 exactly)

// f32 -> bf16 round-to-nearest-even
__device__ __forceinline__ unsigned short f2bf(float f) {
    union { float f; unsigned u; } v; v.f = f;
    unsigned r = v.u + 0x7FFF + ((v.u >> 16) & 1);
    return (unsigned short)(r >> 16);
}
__device__ __forceinline__ float bf2f(unsigned short h) {
    union { unsigned u; float f; } v; v.u = ((unsigned)h) << 16;  return v.f;
}
// packed-bf16 halves of a uint -> f32 (low ushort, high ushort)
__device__ __forceinline__ float blo(unsigned u) {
    union { unsigned u; float f; } v; v.u = u << 16; return v.f;
}
__device__ __forceinline__ float bhi(unsigned u) {
    union { unsigned u; float f; } v; v.u = u & 0xFFFF0000u; return v.f;
}

// R11-verbatim fused kernel: blocks [0, BIN_BLOCKS) bin edges into per-bucket
// regions (bcur zero-based, memset first); blocks [BIN_BLOCKS, ..) T=feat@W1^T.
// NO ncnt histogram (R14: 1.6M global atomics cost ~50us). NO min-waves clause
// (R13: forcing 64 VGPR spilled the binning arrays -> 358us).
__global__ __launch_bounds__(256) void bin_and_gemm1(const int* __restrict__ src,
                                                     const int* __restrict__ dst,
                                                     int* __restrict__ bcur,
                                                     int* __restrict__ binned,
                                                     const float* __restrict__ X,
                                                     const float* __restrict__ W,
                                                     unsigned short* __restrict__ T) {
    __shared__ int cnt[NBK];
    __shared__ int lofs[NBK];
    __shared__ int shiftv[NBK];
    __shared__ int sb[256];
    __shared__ int stag[4096];
    __shared__ unsigned char stb[4096];
    __shared__ float Ws[64 * 64];
    int tid = threadIdx.x;

    if (blockIdx.x >= BIN_BLOCKS) {
        // ---------------- GEMM path (feat f32 -> T bf16) ----------------
#pragma unroll
        for (int j = 0; j < 16; ++j) Ws[j * 256 + tid] = W[j * 256 + tid];
        __syncthreads();

        int n = (blockIdx.x - BIN_BLOCKS) * 256 + tid;
        if (n > N_NODES) return;
        ushort4* tp = (ushort4*)(T + (size_t)n * 64);
        if (n == N_NODES) {  // dummy zero row (pad target for agg1)
            ushort4 z = {0, 0, 0, 0};
#pragma unroll
            for (int k = 0; k < 16; ++k) tp[k] = z;
            return;
        }

        float4 x[16];
        const float4* xp = (const float4*)(X + (size_t)n * 64);
#pragma unroll
        for (int k = 0; k < 16; ++k) x[k] = xp[k];

        for (int fg = 0; fg < 16; ++fg) {
            float r[4];
#pragma unroll
            for (int fi = 0; fi < 4; ++fi) {
                int f = fg * 4 + fi;
                float acc = 0.f;
#pragma unroll
                for (int k4 = 0; k4 < 16; ++k4) {
                    float4 w = *(const float4*)&Ws[f * 64 + k4 * 4];
                    float4 xv = x[k4];
                    acc += xv.x * w.x + xv.y * w.y + xv.z * w.z + xv.w * w.w;
                }
                r[fi] = acc;
            }
            ushort4 o;
            o.x = f2bf(r[0]); o.y = f2bf(r[1]); o.z = f2bf(r[2]); o.w = f2bf(r[3]);
            tp[fg] = o;
        }
        return;
    }

    // ---------------- Binning path (R6-proven) ----------------
    if (tid < NBK) cnt[tid] = 0;
    __syncthreads();

    int base = blockIdx.x * 4096;
    int nedge = N_EDGES - base;
    if (nedge > 4096) nedge = 4096;

    int myb[16], myr[16], myp[16];
#pragma unroll
    for (int i = 0; i < 16; ++i) {
        int e = base + i * 256 + tid;
        myb[i] = -1;
        if (e < N_EDGES) {
            int s = src[e], d = dst[e];
            int b = d >> 8;
            myb[i] = b;
            myp[i] = ((d & 255) << 16) | s;
            myr[i] = atomicAdd(&cnt[b], 1);
        }
    }
    __syncthreads();

    int c = (tid < NBK) ? cnt[tid] : 0;
    sb[tid] = c;
    __syncthreads();
    for (int off = 1; off < 256; off <<= 1) {
        int u = (tid >= off) ? sb[tid - off] : 0;
        __syncthreads();
        sb[tid] += u;
        __syncthreads();
    }
    if (tid < NBK) {
        lofs[tid] = sb[tid] - c;
        if (c) shiftv[tid] = tid * CSR_CAP + atomicAdd(&bcur[tid * 16], c) - lofs[tid];
    }
    __syncthreads();

#pragma unroll
    for (int i = 0; i < 16; ++i) {
        if (myb[i] >= 0) {
            int idx = lofs[myb[i]] + myr[i];
            stag[idx] = myp[i];
            stb[idx] = (unsigned char)myb[i];
        }
    }
    __syncthreads();

    for (int i = tid; i < nedge; i += 256)
        binned[i + shiftv[stb[i]]] = stag[i];
}

// R11-verbatim: one workgroup per (bucket, dst-quarter). Counts padded to
// mult-16 with dummy src = N_NODES (zero row). nodeinfo=(pcnt<<23)|pos, pos%16==0.
__global__ __launch_bounds__(256) void build_csr(const int* __restrict__ binned,
                                                 const int* __restrict__ bcur,
                                                 unsigned* __restrict__ nodeinfo,
                                                 unsigned short* __restrict__ csr16) {
    __shared__ int cnt[64], cnt2[64], ofs[64], sb[64];
    __shared__ int qtot;
    int tid = threadIdx.x;
    int b = blockIdx.x >> 2;
    int q = blockIdx.x & 3;
    int ibase = b * CSR_CAP;
    int qbase = (b * 4 + q) * QCAP;
    int m = bcur[b * 16];          // zero-based bucket edge count
    if (m > CSR_CAP) m = CSR_CAP;
    if (tid < 64) { cnt[tid] = 0; cnt2[tid] = 0; }
    __syncthreads();

    for (int i = tid; i < m; i += 256) {
        int dl = (binned[ibase + i] >> 16) & 255;
        if ((dl >> 6) == q) atomicAdd(&cnt[dl & 63], 1);
    }
    __syncthreads();

    int v = 0;
    if (tid < 64) { v = (cnt[tid] + 15) & ~15; sb[tid] = v; }  // mult-16 pad
    __syncthreads();
    for (int off = 1; off < 64; off <<= 1) {
        int u = (tid >= off && tid < 64) ? sb[tid - off] : 0;
        __syncthreads();
        if (tid < 64) sb[tid] += u;
        __syncthreads();
    }
    if (tid < 64) {
        ofs[tid] = sb[tid] - v;
        int node = (b << 8) + (q << 6) + tid;
        if (node < N_NODES)
            nodeinfo[node] = ((unsigned)v << 23) | (unsigned)(qbase + ofs[tid]);
    }
    if (tid == 63) qtot = sb[63];
    __syncthreads();

    int qt = qtot;
    for (int i = tid; i < qt; i += 256) csr16[qbase + i] = (unsigned short)N_NODES;
    __syncthreads();

    for (int i = tid; i < m; i += 256) {
        int p = binned[ibase + i];
        int dl = (p >> 16) & 255;
        if ((dl >> 6) == q) {
            int r = atomicAdd(&cnt2[dl & 63], 1);
            csr16[qbase + ofs[dl & 63] + r] = (unsigned short)(p & 0xFFFF);
        }
    }
}

// Accumulate one uint4 (8 bf16 feature values) into 8 f32 accumulators.
#define ACC8(d)                                                     \
    a0 += blo(d.x); a1 += bhi(d.x); a2 += blo(d.y); a3 += bhi(d.y); \
    a4 += blo(d.z); a5 += bhi(d.z); a6 += blo(d.w); a7 += bhi(d.w);

// Layer-1 aggregate FUSED with layer-2 transform. R17 concurrency push:
//  - 512 threads / 8 nodes per block; LDS 34.8KB -> 4 blocks/CU = 2048 thr
//    (100% thread-cap occupancy, was 57%).
//  - gather unrolled 4 chunks deep: 4 idx + 4 uint4 row-loads in flight
//    (4KB/wave, was 2KB) to cover L3/HBM miss latency on the random gather.
//  - part[] wave-private, padded to 72 (kills R16's 800K bank-conflict cy);
//    hsf overlaid into part row 0 (wave-internal, needs no barrier).
//  - single __syncthreads (W2 staging only). csr/nodeinfo loads nontemporal
//    (streams must not evict T from the 4MB per-XCD L2).
__global__ __launch_bounds__(512) void agg_fuse1(const unsigned short* __restrict__ T,
                                                 const unsigned short* __restrict__ csr,
                                                 const unsigned* __restrict__ nodeinfo,
                                                 const float* __restrict__ b1,
                                                 const float* __restrict__ W2,
                                                 unsigned short* __restrict__ T2) {
    __shared__ __align__(16) float4 W2t4[1024];     // 16 KB (W2 transposed, lane-striped)
    __shared__ __align__(16) float part[8][8][72];  // 18 KB (per-wave partials; row0 doubles as h)
    int tid = threadIdx.x;
    int w = tid >> 6;
    int lane = tid & 63;
    int g8 = lane >> 3;
    int fs = lane & 7;
    int node = blockIdx.x * 8 + w;

    // stage W2 transposed (read after the single barrier below)
    for (int L4 = tid; L4 < 1024; L4 += 512) {
        int k4 = L4 >> 6, f = L4 & 63;
        W2t4[L4] = *(const float4*)(W2 + f * 64 + k4 * 4);
    }

    // ---- gather-accumulate: 8 rows/load, 4 loads in flight ----
    unsigned info = __builtin_nontemporal_load(nodeinfo + node);
    float bias = b1[lane];
    int pos = (int)(info & 0x7FFFFFu);
    int nch = (int)(info >> 23) >> 3;   // 8-edge chunks, even (pcnt mult 16)
    const unsigned short* ip = csr + pos + g8;
    const uint4* Tp = (const uint4*)T;
    float a0 = 0.f, a1 = 0.f, a2 = 0.f, a3 = 0.f, a4 = 0.f, a5 = 0.f, a6 = 0.f, a7 = 0.f;
    int c = 0;
    for (; c + 4 <= nch; c += 4) {
        int j0 = __builtin_nontemporal_load(ip + c * 8);
        int j1 = __builtin_nontemporal_load(ip + c * 8 + 8);
        int j2 = __builtin_nontemporal_load(ip + c * 8 + 16);
        int j3 = __builtin_nontemporal_load(ip + c * 8 + 24);
        uint4 d0 = Tp[j0 * 8 + fs];
        uint4 d1 = Tp[j1 * 8 + fs];
        uint4 d2 = Tp[j2 * 8 + fs];
        uint4 d3 = Tp[j3 * 8 + fs];
        ACC8(d0) ACC8(d1) ACC8(d2) ACC8(d3)
    }
    if (c < nch) {   // remaining 2 chunks (nch even)
        int j0 = __builtin_nontemporal_load(ip + c * 8);
        int j1 = __builtin_nontemporal_load(ip + c * 8 + 8);
        uint4 d0 = Tp[j0 * 8 + fs];
        uint4 d1 = Tp[j1 * 8 + fs];
        ACC8(d0) ACC8(d1)
    }
    float4 pa = {a0, a1, a2, a3};
    float4 pb = {a4, a5, a6, a7};
    *(float4*)&part[w][g8][fs * 8] = pa;
    *(float4*)&part[w][g8][fs * 8 + 4] = pb;
    __syncthreads();   // covers W2t4 staging (part is wave-private)

    // reduce 8 groups: lane = feature
    float acc = bias;
#pragma unroll
    for (int g = 0; g < 8; ++g) acc += part[w][g][lane];

    // ---- tanh + in-block 64x64 GEMM epilogue (h overlaid in part row 0) ----
    float e = __expf(2.f * acc);
    part[w][0][lane] = 1.f - 2.f / (e + 1.f);   // after all part reads (lockstep wave)

    const float* hrow = &part[w][0][0];
    float tf = 0.f;
#pragma unroll
    for (int k4 = 0; k4 < 16; ++k4) {
        float4 hv = *(const float4*)(hrow + k4 * 4);   // broadcast
        float4 wv = W2t4[k4 * 64 + lane];
        tf += hv.x * wv.x + hv.y * wv.y + hv.z * wv.z + hv.w * wv.w;
    }
    T2[(size_t)node * DIM + lane] = f2bf(tf);

    // zero T2's dummy pad row (block 0 only; agg2 gathers it for padding)
    if (blockIdx.x == 0 && tid < 64)
        T2[(size_t)N_NODES * DIM + tid] = 0;
}

// Layer-2 aggregate: out = gather-sum(T2) + b2, f32. Same gather structure;
// no W2 epilogue -> no barrier at all.
__global__ __launch_bounds__(512) void agg_out(const unsigned short* __restrict__ T,
                                               const unsigned short* __restrict__ csr,
                                               const unsigned* __restrict__ nodeinfo,
                                               const float* __restrict__ bias,
                                               float* __restrict__ outp) {
    __shared__ __align__(16) float part[8][8][72];  // 18 KB, wave-private
    int tid = threadIdx.x;
    int w = tid >> 6;
    int lane = tid & 63;
    int g8 = lane >> 3;
    int fs = lane & 7;
    int node = blockIdx.x * 8 + w;   // grid*8 == 50000 exactly

    unsigned info = __builtin_nontemporal_load(nodeinfo + node);
    float bv = bias[lane];
    int pos = (int)(info & 0x7FFFFFu);
    int nch = (int)(info >> 23) >> 3;
    const unsigned short* ip = csr + pos + g8;
    const uint4* Tp = (const uint4*)T;
    float a0 = 0.f, a1 = 0.f, a2 = 0.f, a3 = 0.f, a4 = 0.f, a5 = 0.f, a6 = 0.f, a7 = 0.f;
    int c = 0;
    for (; c + 4 <= nch; c += 4) {
        int j0 = __builtin_nontemporal_load(ip + c * 8);
        int j1 = __builtin_nontemporal_load(ip + c * 8 + 8);
        int j2 = __builtin_nontemporal_load(ip + c * 8 + 16);
        int j3 = __builtin_nontemporal_load(ip + c * 8 + 24);
        uint4 d0 = Tp[j0 * 8 + fs];
        uint4 d1 = Tp[j1 * 8 + fs];
        uint4 d2 = Tp[j2 * 8 + fs];
        uint4 d3 = Tp[j3 * 8 + fs];
        ACC8(d0) ACC8(d1) ACC8(d2) ACC8(d3)
    }
    if (c < nch) {
        int j0 = __builtin_nontemporal_load(ip + c * 8);
        int j1 = __builtin_nontemporal_load(ip + c * 8 + 8);
        uint4 d0 = Tp[j0 * 8 + fs];
        uint4 d1 = Tp[j1 * 8 + fs];
        ACC8(d0) ACC8(d1)
    }
    float4 pa = {a0, a1, a2, a3};
    float4 pb = {a4, a5, a6, a7};
    *(float4*)&part[w][g8][fs * 8] = pa;
    *(float4*)&part[w][g8][fs * 8 + 4] = pb;
    // part is wave-private: wave-internal lgkmcnt ordering suffices, no barrier

    float acc = bv;
#pragma unroll
    for (int g = 0; g < 8; ++g) acc += part[w][g][lane];
    __builtin_nontemporal_store(acc, outp + (size_t)node * DIM + lane);
}

extern "C" void kernel_launch(void* const* d_in, const int* in_sizes, int n_in,
                              void* d_out, int out_size, void* d_ws, size_t ws_size,
                              hipStream_t stream) {
    const float* feat = (const float*)d_in[0];
    const int*   src  = (const int*)d_in[1];
    const int*   dst  = (const int*)d_in[2];
    const float* W1   = (const float*)d_in[3];
    const float* b1   = (const float*)d_in[4];
    const float* W2   = (const float*)d_in[5];
    const float* b2   = (const float*)d_in[6];
    float* out = (float*)d_out;

    // ws layout (~27.9 MB; harness poisons 256 MB of ws -> plenty)
    int*            binned   = (int*)d_ws;                                // 196*12288 ints
    unsigned short* csr16    = (unsigned short*)(binned + NBK * CSR_CAP); // 784*3072 ushort
    unsigned*       nodeinfo = (unsigned*)(csr16 + NBK * 4 * QCAP);       // 50000
    int*            bcur     = (int*)(nodeinfo + N_NODES);                // 196*16
    unsigned short* t        = (unsigned short*)(bcur + NBK * 16 + 8);    // 50001*64 bf16
    unsigned short* t2       = t + (size_t)(N_NODES + 1) * 64;            // 50001*64 bf16

    // ---- CSR build + layer-1 transform (overlapped) ----
    hipMemsetAsync(bcur, 0, NBK * 16 * sizeof(int), stream);
    bin_and_gemm1<<<BIN_BLOCKS + GEMM_BLOCKS, 256, 0, stream>>>(
        src, dst, bcur, binned, feat, W1, t);
    build_csr<<<NBK * 4, 256, 0, stream>>>(binned, bcur, nodeinfo, csr16);

    // ---- Layer 1 aggregate + fused layer-2 transform: t2 = tanh(agg+b1)@W2^T ----
    agg_fuse1<<<NB_AGG8, 512, 0, stream>>>(t, csr16, nodeinfo, b1, W2, t2);

    // ---- Layer 2 aggregate: out = agg(t2) + b2, f32 ----
    agg_out<<<NB_AGG8, 512, 0, stream>>>(t2, csr16, nodeinfo, b2, out);
}